// Round 14
// baseline (277.104 us; speedup 1.0000x reference)
//
#include <hip/hip_runtime.h>
#include <hip/hip_bf16.h>
#include <math.h>

#define N_NODES 50000
#define NEDGE 1600000
#define BN_EPS 1e-5f
#define G1_BLOCKS 1563  // ceil(50000/32)
#define EB 1563         // ceil((NEDGE/4)/256)
#define SB 128          // partial-reduction blocks
#define NBUCK 196       // coarse buckets (row >> 8)
#define BCAP 10240      // bucket capacity (avg 8163, sigma~90 -> 23 sigma)

__device__ inline float bf2f(ushort u) {
  union { unsigned i; float f; } v;
  v.i = ((unsigned)u) << 16;
  return v.f;
}
__device__ inline ushort f2bf(float x) {
  __hip_bfloat16 b = __float2bfloat16(x);
  return *(ushort*)&b;
}

// ---------------------------------------------------------------------------
// Fused: even blocks -> GEMM1 32-row tile (EXACT R13); odd blocks -> binning
// pass 1 (LDS-histogram into 196 coarse buckets, 196 global atomics/block).
// ---------------------------------------------------------------------------
__global__ __launch_bounds__(256) void gemm1_bin_kernel(
    const float4* __restrict__ X4, const float4* __restrict__ W4,
    ushort* __restrict__ C, const int4* __restrict__ row4,
    const int4* __restrict__ col4, const float4* __restrict__ vals4,
    int* __restrict__ gcur, uint2* __restrict__ bdata) {
  __shared__ float4 sW[64 * 32];   // 32KB
  __shared__ float4 sX[32 * 32];   // 16KB
  const int t = threadIdx.x;

  if (blockIdx.x & 1) {  // ---- binning pass 1 (aliases sW's LDS) ----
    int* bcnt = (int*)sW;            // 256 ints
    int* bbase = bcnt + 256;         // 256 ints
    int* lcur = bbase + 256;         // 256 ints
    uint2* stage = (uint2*)(lcur + 256);  // 1024 uint2 = 8KB
    for (int i = t; i < NBUCK; i += 256) bcnt[i] = 0;
    __syncthreads();
    int i4 = (blockIdx.x >> 1) * 256 + t;
    bool valid = i4 < NEDGE / 4;
    if (valid) {
      int4 r = row4[i4];
      int4 c = col4[i4];
      float4 v = vals4[i4];
      atomicAdd(&bcnt[r.x >> 8], 1);
      atomicAdd(&bcnt[r.y >> 8], 1);
      atomicAdd(&bcnt[r.z >> 8], 1);
      atomicAdd(&bcnt[r.w >> 8], 1);
      stage[t * 4 + 0] = make_uint2((unsigned)r.x,
                                    ((unsigned)c.x << 16) | f2bf(v.x));
      stage[t * 4 + 1] = make_uint2((unsigned)r.y,
                                    ((unsigned)c.y << 16) | f2bf(v.y));
      stage[t * 4 + 2] = make_uint2((unsigned)r.z,
                                    ((unsigned)c.z << 16) | f2bf(v.z));
      stage[t * 4 + 3] = make_uint2((unsigned)r.w,
                                    ((unsigned)c.w << 16) | f2bf(v.w));
    }
    __syncthreads();
    if (t < NBUCK) {
      lcur[t] = 0;
      bbase[t] = bcnt[t] ? atomicAdd(&gcur[t], bcnt[t]) : 0;
    }
    __syncthreads();
    if (valid) {
#pragma unroll
      for (int k = 0; k < 4; ++k) {
        uint2 e = stage[t * 4 + k];
        int b = e.x >> 8;
        int pos = bbase[b] + atomicAdd(&lcur[b], 1);
        if (pos < BCAP) bdata[(long)b * BCAP + pos] = e;
      }
    }
    return;
  }

  // ---- gemm1 part (EXACT R13) ----
  float* Xl = (float*)sX;
  const int r0 = (blockIdx.x >> 1) * 32;

  for (int i = t; i < 1024; i += 256) {
    int rr = i >> 5;
    int r = r0 + rr;
    sX[i] = (r < N_NODES) ? X4[(long)r * 32 + (i & 31)]
                          : make_float4(0.f, 0.f, 0.f, 0.f);
  }

  const int tx = t & 31;
  const int ty = t >> 5;
  float acc[4][4] = {{0.f}};

  for (int kt = 0; kt < 2; ++kt) {
    __syncthreads();
    for (int i = t; i < 2048; i += 256) sW[i] = W4[kt * 2048 + i];
    __syncthreads();
    const int kbase = kt * 64;
#pragma unroll 8
    for (int kk = 0; kk < 64; ++kk) {
      float4 wv = sW[kk * 32 + tx];
      float x0 = Xl[(ty * 4 + 0) * 128 + kbase + kk];
      float x1 = Xl[(ty * 4 + 1) * 128 + kbase + kk];
      float x2 = Xl[(ty * 4 + 2) * 128 + kbase + kk];
      float x3 = Xl[(ty * 4 + 3) * 128 + kbase + kk];
      acc[0][0] += x0 * wv.x; acc[0][1] += x0 * wv.y;
      acc[0][2] += x0 * wv.z; acc[0][3] += x0 * wv.w;
      acc[1][0] += x1 * wv.x; acc[1][1] += x1 * wv.y;
      acc[1][2] += x1 * wv.z; acc[1][3] += x1 * wv.w;
      acc[2][0] += x2 * wv.x; acc[2][1] += x2 * wv.y;
      acc[2][2] += x2 * wv.z; acc[2][3] += x2 * wv.w;
      acc[3][0] += x3 * wv.x; acc[3][1] += x3 * wv.y;
      acc[3][2] += x3 * wv.z; acc[3][3] += x3 * wv.w;
    }
  }
  for (int j = 0; j < 4; ++j) {
    int r = r0 + ty * 4 + j;
    if (r < N_NODES) {
      ushort4 o;
      o.x = f2bf(acc[j][0]); o.y = f2bf(acc[j][1]);
      o.z = f2bf(acc[j][2]); o.w = f2bf(acc[j][3]);
      *(ushort4*)&C[(long)r * 128 + tx * 4] = o;
    }
  }
}

// ---------------------------------------------------------------------------
// Pass 2: per-bucket in-LDS counting sort, with inline prefix-scan of gcur
// (replaces the separate bscan kernel). Zero global atomics.
// ---------------------------------------------------------------------------
__global__ __launch_bounds__(512) void sort_kernel(
    const uint2* __restrict__ bdata, const int* __restrict__ gcur,
    int* __restrict__ rowptr, unsigned* __restrict__ ep) {
  const int b = blockIdx.x;   // 196 buckets
  const int t = threadIdx.x;  // 512
  __shared__ int rcnt[256], roff[256], cur[256];
  __shared__ int gsc[256];
  __shared__ unsigned eps[BCAP];  // 40KB
  // inline exclusive prefix of bucket totals
  int gv = (t < NBUCK) ? gcur[t] : 0;
  if (t < 256) gsc[t] = gv;
  __syncthreads();
  for (int off = 1; off < 256; off <<= 1) {
    int x = 0;
    if (t < 256 && t >= off) x = gsc[t - off];
    __syncthreads();
    if (t < 256) gsc[t] += x;
    __syncthreads();
  }
  int total = gcur[b];
  if (total > BCAP) total = BCAP;
  int base = gsc[b] - gcur[b];  // exclusive prefix
  if (t < 256) rcnt[t] = 0;
  __syncthreads();
  for (int i = t; i < total; i += 512) {
    uint2 e = bdata[(long)b * BCAP + i];
    atomicAdd(&rcnt[e.x & 255], 1);
  }
  __syncthreads();
  if (t < 256) roff[t] = rcnt[t];
  __syncthreads();
  for (int off = 1; off < 256; off <<= 1) {
    int x = 0;
    if (t < 256 && t >= off) x = roff[t - off];
    __syncthreads();
    if (t < 256) roff[t] += x;
    __syncthreads();
  }
  if (t < 256) {
    int excl = roff[t] - rcnt[t];
    cur[t] = excl;
    int grow = b * 256 + t;
    if (grow < N_NODES) rowptr[grow] = base + excl;
  }
  if (b == NBUCK - 1 && t == 0) rowptr[N_NODES] = NEDGE;
  __syncthreads();
  for (int i = t; i < total; i += 512) {
    uint2 e = bdata[(long)b * BCAP + i];
    int p = atomicAdd(&cur[e.x & 255], 1);
    eps[p] = e.y;
  }
  __syncthreads();
  for (int i = t; i < total; i += 512) ep[base + i] = eps[i];
}

// ---------------------------------------------------------------------------
// Gather-SpMM, 128 feats: one wave per row, unroll-8 edges (R10-validated).
// ---------------------------------------------------------------------------
__global__ __launch_bounds__(256) void gather128_kernel(
    const int* __restrict__ rowptr, const unsigned* __restrict__ ep,
    const ushort* __restrict__ S, ushort2* __restrict__ H) {
  int r = (blockIdx.x * 256 + threadIdx.x) >> 6;
  int lane = threadIdx.x & 63;
  if (r >= N_NODES) return;
  int b = rowptr[r], e2 = rowptr[r + 1];
  float ax[8], ay[8];
#pragma unroll
  for (int i = 0; i < 8; ++i) { ax[i] = 0.f; ay[i] = 0.f; }
  int e = b;
  for (; e + 7 < e2; e += 8) {
    unsigned u[8];
    ushort2 s[8];
#pragma unroll
    for (int i = 0; i < 8; ++i) u[i] = ep[e + i];
#pragma unroll
    for (int i = 0; i < 8; ++i)
      s[i] = ((const ushort2*)(S + (long)(u[i] >> 16) * 128))[lane];
#pragma unroll
    for (int i = 0; i < 8; ++i) {
      float v = bf2f((ushort)u[i]);
      ax[i] += v * bf2f(s[i].x);
      ay[i] += v * bf2f(s[i].y);
    }
  }
  for (; e < e2; ++e) {
    unsigned u0 = ep[e];
    float v0 = bf2f((ushort)u0);
    ushort2 s0 = ((const ushort2*)(S + (long)(u0 >> 16) * 128))[lane];
    ax[0] += v0 * bf2f(s0.x);
    ay[0] += v0 * bf2f(s0.y);
  }
  float hx = ((ax[0] + ax[1]) + (ax[2] + ax[3])) +
             ((ax[4] + ax[5]) + (ax[6] + ax[7]));
  float hy = ((ay[0] + ay[1]) + (ay[2] + ay[3])) +
             ((ay[4] + ay[5]) + (ay[6] + ay[7]));
  H[(long)r * 64 + lane] = make_ushort2(f2bf(hx), f2bf(hy));
}

// ---------------------------------------------------------------------------
// Stats over bf16 H1: partials + ticketed last-block reduce (R10-validated)
// ---------------------------------------------------------------------------
__global__ __launch_bounds__(256) void statsbf_kernel(
    const ushort* __restrict__ H, float* __restrict__ part_s,
    float* __restrict__ part_q, int* __restrict__ ticket,
    float* __restrict__ s, float* __restrict__ ss) {
  const int t = threadIdx.x;
  const int cg = t & 31;
  const int rg = t >> 5;
  float sum0 = 0.f, sum1 = 0.f, sum2 = 0.f, sum3 = 0.f;
  float sq0 = 0.f, sq1 = 0.f, sq2 = 0.f, sq3 = 0.f;
  for (int r = blockIdx.x * 8 + rg; r < N_NODES; r += SB * 8) {
    ushort4 u = *(const ushort4*)(H + (long)r * 128 + cg * 4);
    float x0 = bf2f(u.x), x1 = bf2f(u.y), x2 = bf2f(u.z), x3 = bf2f(u.w);
    sum0 += x0; sq0 += x0 * x0;
    sum1 += x1; sq1 += x1 * x1;
    sum2 += x2; sq2 += x2 * x2;
    sum3 += x3; sq3 += x3 * x3;
  }
  __shared__ float lds[8][128];
  lds[rg][cg * 4 + 0] = sum0; lds[rg][cg * 4 + 1] = sum1;
  lds[rg][cg * 4 + 2] = sum2; lds[rg][cg * 4 + 3] = sum3;
  __syncthreads();
  if (t < 128) {
    float x = 0.f;
#pragma unroll
    for (int g = 0; g < 8; ++g) x += lds[g][t];
    part_s[blockIdx.x * 128 + t] = x;
  }
  __syncthreads();
  lds[rg][cg * 4 + 0] = sq0; lds[rg][cg * 4 + 1] = sq1;
  lds[rg][cg * 4 + 2] = sq2; lds[rg][cg * 4 + 3] = sq3;
  __syncthreads();
  if (t < 128) {
    float x = 0.f;
#pragma unroll
    for (int g = 0; g < 8; ++g) x += lds[g][t];
    part_q[blockIdx.x * 128 + t] = x;
  }
  __shared__ bool isLast;
  __threadfence();
  if (t == 0) isLast = (atomicAdd(ticket, 1) == SB - 1);
  __syncthreads();
  if (isLast && t < 128) {
    float a = 0.f, bq = 0.f;
    for (int i = 0; i < SB; ++i) {
      a += part_s[i * 128 + t];
      bq += part_q[i * 128 + t];
    }
    s[t] = a;
    ss[t] = bq;
  }
}

// ---------------------------------------------------------------------------
// GEMM2 (EXACT R13)
// ---------------------------------------------------------------------------
__global__ __launch_bounds__(256) void gemm2_kernel(
    const ushort* __restrict__ Hbf, const float4* __restrict__ W4,
    const float* __restrict__ s1, const float* __restrict__ ss1,
    const float* __restrict__ gamma, const float* __restrict__ beta,
    ushort* __restrict__ C) {
  __shared__ float4 sW[128 * 16];  // 32KB
  __shared__ float4 sX[32 * 32];   // 16KB
  __shared__ float sA[128], sB[128];
  const int t = threadIdx.x;

  if (t < 128) {
    float mean = s1[t] * (1.0f / N_NODES);
    float var = ss1[t] * (1.0f / N_NODES) - mean * mean;
    float a = gamma[t] * rsqrtf(var + BN_EPS);
    sA[t] = a;
    sB[t] = beta[t] - a * mean;
  }
  for (int i = t; i < 2048; i += 256) sW[i] = W4[i];
  __syncthreads();

  const int r0 = blockIdx.x * 32;
  for (int i = t; i < 1024; i += 256) {
    int rr = i >> 5;
    int r = r0 + rr;
    int c4 = i & 31;
    float4 v = make_float4(0.f, 0.f, 0.f, 0.f);
    if (r < N_NODES) {
      ushort4 u = *(const ushort4*)(Hbf + (long)r * 128 + c4 * 4);
      float4 a4 = *(const float4*)&sA[c4 * 4];
      float4 b4 = *(const float4*)&sB[c4 * 4];
      v.x = fmaxf(a4.x * bf2f(u.x) + b4.x, 0.f);
      v.y = fmaxf(a4.y * bf2f(u.y) + b4.y, 0.f);
      v.z = fmaxf(a4.z * bf2f(u.z) + b4.z, 0.f);
      v.w = fmaxf(a4.w * bf2f(u.w) + b4.w, 0.f);
    }
    sX[i] = v;
  }
  __syncthreads();

  const int tx = t & 15;
  const int ty = t >> 4;
  float acc[2][4] = {{0.f}};
  float* Xl = (float*)sX;
#pragma unroll 8
  for (int k = 0; k < 128; ++k) {
    float4 wv = sW[k * 16 + tx];
    float x0 = Xl[(ty * 2 + 0) * 128 + k];
    float x1 = Xl[(ty * 2 + 1) * 128 + k];
    acc[0][0] += x0 * wv.x; acc[0][1] += x0 * wv.y;
    acc[0][2] += x0 * wv.z; acc[0][3] += x0 * wv.w;
    acc[1][0] += x1 * wv.x; acc[1][1] += x1 * wv.y;
    acc[1][2] += x1 * wv.z; acc[1][3] += x1 * wv.w;
  }
  for (int j = 0; j < 2; ++j) {
    int r = r0 + ty * 2 + j;
    if (r < N_NODES) {
      ushort4 o;
      o.x = f2bf(acc[j][0]); o.y = f2bf(acc[j][1]);
      o.z = f2bf(acc[j][2]); o.w = f2bf(acc[j][3]);
      *(ushort4*)&C[(long)r * 64 + tx * 4] = o;
    }
  }
}

// ---------------------------------------------------------------------------
// Gather-SpMM, 64 feats: half-wave per row, unroll-8, bf16 src, f32 out.
// ---------------------------------------------------------------------------
__global__ __launch_bounds__(256) void gather64_kernel(
    const int* __restrict__ rowptr, const unsigned* __restrict__ ep,
    const ushort* __restrict__ S, float2* __restrict__ H) {
  int r = (blockIdx.x * 256 + threadIdx.x) >> 5;
  int sub = threadIdx.x & 31;
  if (r >= N_NODES) return;
  int b = rowptr[r], e2 = rowptr[r + 1];
  float ax[8], ay[8];
#pragma unroll
  for (int i = 0; i < 8; ++i) { ax[i] = 0.f; ay[i] = 0.f; }
  int e = b;
  for (; e + 7 < e2; e += 8) {
    unsigned u[8];
    ushort2 s[8];
#pragma unroll
    for (int i = 0; i < 8; ++i) u[i] = ep[e + i];
#pragma unroll
    for (int i = 0; i < 8; ++i)
      s[i] = ((const ushort2*)(S + (long)(u[i] >> 16) * 64))[sub];
#pragma unroll
    for (int i = 0; i < 8; ++i) {
      float v = bf2f((ushort)u[i]);
      ax[i] += v * bf2f(s[i].x);
      ay[i] += v * bf2f(s[i].y);
    }
  }
  for (; e < e2; ++e) {
    unsigned u0 = ep[e];
    float v0 = bf2f((ushort)u0);
    ushort2 s0 = ((const ushort2*)(S + (long)(u0 >> 16) * 64))[sub];
    ax[0] += v0 * bf2f(s0.x);
    ay[0] += v0 * bf2f(s0.y);
  }
  float hx = ((ax[0] + ax[1]) + (ax[2] + ax[3])) +
             ((ax[4] + ax[5]) + (ax[6] + ax[7]));
  float hy = ((ay[0] + ay[1]) + (ay[2] + ay[3])) +
             ((ay[4] + ay[5]) + (ay[6] + ay[7]));
  H[(long)r * 32 + sub] = make_float2(hx, hy);
}

// ---------------------------------------------------------------------------
// Stats over f32 H2: partials + ticketed last-block reduce (R10-validated)
// ---------------------------------------------------------------------------
__global__ __launch_bounds__(256) void stats64_kernel(
    const float* __restrict__ H, float* __restrict__ part_s,
    float* __restrict__ part_q, int* __restrict__ ticket,
    float* __restrict__ s, float* __restrict__ ss) {
  const int t = threadIdx.x;
  const int c = t & 63;
  const int rg = t >> 6;
  float sum = 0.f, sq = 0.f;
  for (int r = blockIdx.x * 4 + rg; r < N_NODES; r += SB * 4) {
    float x = H[(long)r * 64 + c];
    sum += x;
    sq += x * x;
  }
  __shared__ float lds[4][64];
  lds[rg][c] = sum;
  __syncthreads();
  if (t < 64)
    part_s[blockIdx.x * 64 + t] =
        lds[0][t] + lds[1][t] + lds[2][t] + lds[3][t];
  __syncthreads();
  lds[rg][c] = sq;
  __syncthreads();
  if (t < 64)
    part_q[blockIdx.x * 64 + t] =
        lds[0][t] + lds[1][t] + lds[2][t] + lds[3][t];
  __shared__ bool isLast;
  __threadfence();
  if (t == 0) isLast = (atomicAdd(ticket, 1) == SB - 1);
  __syncthreads();
  if (isLast && t < 64) {
    float a = 0.f, bq = 0.f;
    for (int i = 0; i < SB; ++i) {
      a += part_s[i * 64 + t];
      bq += part_q[i * 64 + t];
    }
    s[t] = a;
    ss[t] = bq;
  }
}

// ---------------------------------------------------------------------------
// Final: partials + ticketed last-block reduce + bias + sigmoid -> out
// ---------------------------------------------------------------------------
__global__ __launch_bounds__(256) void final_kernel(
    const float* __restrict__ H, const float* __restrict__ Wm,
    const float* __restrict__ s2, const float* __restrict__ ss2,
    const float* __restrict__ gamma, const float* __restrict__ beta,
    const float* __restrict__ bm, float* __restrict__ partF,
    int* __restrict__ ticket, float* __restrict__ out) {
  const int t = threadIdx.x;
  const int c = t & 63;
  const int rg = t >> 6;
  float mean = s2[c] * (1.0f / N_NODES);
  float var = ss2[c] * (1.0f / N_NODES) - mean * mean;
  float a = gamma[c] * rsqrtf(var + BN_EPS);
  float b = beta[c] - a * mean;
  float sum = 0.f;
  for (int r = blockIdx.x * 4 + rg; r < N_NODES; r += SB * 4) {
    float x = fmaxf(a * H[(long)r * 64 + c] + b, 0.f);
    sum += x * Wm[(long)r * 64 + c];
  }
  __shared__ float lds[4][64];
  lds[rg][c] = sum;
  __syncthreads();
  if (t < 64)
    partF[blockIdx.x * 64 + t] =
        lds[0][t] + lds[1][t] + lds[2][t] + lds[3][t];
  __shared__ bool isLast;
  __threadfence();
  if (t == 0) isLast = (atomicAdd(ticket, 1) == SB - 1);
  __syncthreads();
  if (isLast && t < 64) {
    float x = bm[t];
    for (int i = 0; i < SB; ++i) x += partF[i * 64 + t];
    out[t] = 1.0f / (1.0f + expf(-x));
  }
}

// ---------------------------------------------------------------------------
extern "C" void kernel_launch(void* const* d_in, const int* in_sizes, int n_in,
                              void* d_out, int out_size, void* d_ws,
                              size_t ws_size, hipStream_t stream) {
  const float* emb  = (const float*)d_in[0];
  const float* W1   = (const float*)d_in[1];
  // d_in[2] = b1: cancels exactly under BN
  const float* g1   = (const float*)d_in[3];
  const float* be1  = (const float*)d_in[4];
  const float* W2   = (const float*)d_in[5];
  // d_in[6] = b2: cancels under BN
  const float* g2   = (const float*)d_in[7];
  const float* be2  = (const float*)d_in[8];
  const float* Wm   = (const float*)d_in[9];
  const float* bm   = (const float*)d_in[10];
  // d_in[11] = vertices = arange(N): identity gather
  const int* row    = (const int*)d_in[12];
  const int* col    = (const int*)d_in[13];
  const float* vals = (const float*)d_in[14];

  // workspace layout: bdata (16.1MB) aliases h1+h2 (dead until gather128)
  ushort*   sup    = (ushort*)d_ws;              // 6.4M bf16 (12.8 MB)
  ushort*   h1     = sup + 6400000;              // 6.4M bf16 (12.8 MB)
  float*    h2     = (float*)(h1 + 6400000);     // 3.2M f32 (12.8 MB)
  uint2*    bdata  = (uint2*)h1;                 // 196*10240*8B = 16.06 MB
  unsigned* ep     = (unsigned*)(h2 + 3200000);  // 1.6M u32 (6.4 MB)
  int*      rowptr = (int*)(ep + 1600000);       // 50,001
  int*      gcur   = rowptr + 50001;             // 256
  int*      tick   = gcur + 256;                 // 8 (zeroed with gcur)
  float*    part_s = (float*)(tick + 8);         // SB*128
  float*    part_q = part_s + SB * 128;          // SB*128
  float*    partF  = part_q + SB * 128;          // SB*64
  float*    s1     = partF + SB * 64;            // 128
  float*    ss1    = s1 + 128;                   // 128
  float*    s2     = ss1 + 128;                  // 64
  float*    ss2    = s2 + 64;                    // 64
  float*    out = (float*)d_out;

  hipMemsetAsync(gcur, 0, 264 * sizeof(int), stream);

  // ---- GEMM1 + binning pass 1 fused (even=gemm, odd=bin) ----
  gemm1_bin_kernel<<<G1_BLOCKS + EB, 256, 0, stream>>>(
      (const float4*)emb, (const float4*)W1, sup, (const int4*)row,
      (const int4*)col, (const float4*)vals, gcur, bdata);

  // ---- per-bucket in-LDS sort (inline bucket-prefix scan) ----
  sort_kernel<<<NBUCK, 512, 0, stream>>>(bdata, gcur, rowptr, ep);

  // ---- Layer 1 aggregate + stats ----
  gather128_kernel<<<(N_NODES * 64 + 255) / 256, 256, 0, stream>>>(
      rowptr, ep, sup, (ushort2*)h1);
  statsbf_kernel<<<SB, 256, 0, stream>>>(h1, part_s, part_q, &tick[0], s1,
                                         ss1);

  // ---- Layer 2 ----
  gemm2_kernel<<<G1_BLOCKS, 256, 0, stream>>>(h1, (const float4*)W2, s1, ss1,
                                              g1, be1, sup);
  gather64_kernel<<<(N_NODES * 32 + 255) / 256, 256, 0, stream>>>(
      rowptr, ep, sup, (float2*)h2);
  stats64_kernel<<<SB, 256, 0, stream>>>(h2, part_s, part_q, &tick[1], s2,
                                         ss2);

  // ---- MaskLinear + sigmoid ----
  final_kernel<<<SB, 256, 0, stream>>>(h2, Wm, s2, ss2, g2, be2, bm, partF,
                                       &tick[2], out);
}